// Round 2
// baseline (751.822 us; speedup 1.0000x reference)
//
#include <hip/hip_runtime.h>

#define NNODES 468
#define NT 128        // output nodes per block
#define KT 32         // k-tile
#define DOB 128       // output columns per block
#define YS_STR 36     // Ys row stride in floats (9 float4) — bank-offset 4/row
#define WS_STR 132    // Ws row stride in floats (33 float4)

// ---------------------------------------------------------------------------
// Fused GCN layer, aggregate-first:  Out = relu( ((A@X) @ W) + bias )
// A = banded normalized adjacency (|i-j|<=9, incl self-loop), norm separable:
//   norm(i,j) = dinv[i]*dinv[j]  ->  Y[i] = dinv[i] * rolling_sum_j dinv[j]X[j]
// ENCODE: X is computed on the fly from landmarks (node encoder fused).
// POOL:   instead of storing X, emit per-tile column sums (mean-pool partials).
// ---------------------------------------------------------------------------
template<int D_IN, bool ENCODE, bool POOL, int MINW>
__global__ __launch_bounds__(256, MINW) void gcn(
    const float* __restrict__ Xin, const float* __restrict__ W,
    const float* __restrict__ bias, float* __restrict__ Out,
    const float* __restrict__ We, const float* __restrict__ be,
    int dot)
{
    __shared__ __align__(16) float Ys[NT * YS_STR];   // 4608 f
    __shared__ __align__(16) float Ws[KT * WS_STR];   // 4224 f
    __shared__ float dinvs[148];                      // nodes n0-9 .. n0+136

    const int tid  = threadIdx.x;
    const int tile = blockIdx.x;
    const int b    = blockIdx.y;
    const int c0   = blockIdx.z * DOB;
    const int n0   = tile * NT;

    if (tid < NT + 18) {
        int node = n0 - 9 + tid;
        int lo = node - 9; if (lo < 0) lo = 0;
        int hi = node + 9; if (hi > NNODES - 1) hi = NNODES - 1;
        int deg = hi - lo + 1; if (deg < 1) deg = 1;
        dinvs[tid] = 1.0f / sqrtf((float)deg);
    }

    const int cx = tid & 15;   // 16 column groups x 8 cols
    const int ry = tid >> 4;   // 16 row groups; thread rows = ry + 16*i

    float acc[8][8];
    #pragma unroll
    for (int i = 0; i < 8; ++i)
        #pragma unroll
        for (int j = 0; j < 8; ++j) acc[i][j] = 0.f;

    const float* Xb = ENCODE ? (Xin + (size_t)b * (NNODES * 3))
                             : (Xin + (size_t)b * NNODES * D_IN);

    const int kk = tid & 31;   // staged column within k-tile
    const int sl = tid >> 5;   // row slice: rows sl*16 .. sl*16+15
    const int r0 = sl * 16;

    for (int k0 = 0; k0 < D_IN; k0 += KT) {
        __syncthreads();   // Ys/Ws reuse from previous iter; dinvs on iter 0

        // ---- stage Ws[KT][DOB] ----
        for (int i = tid; i < KT * (DOB / 4); i += 256) {
            int row = i >> 5;
            int c4  = (i & 31) << 2;
            *(float4*)(Ws + row * WS_STR + c4) =
                *(const float4*)(W + (size_t)(k0 + row) * dot + c0 + c4);
        }

        // ---- stage Ys = (A @ X)[n0..n0+127][k0+kk] via rolling window ----
        {
            const int k = k0 + kk;
            float w0 = 0.f, w1 = 0.f, w2 = 0.f, bk = 0.f;
            const float* xp = nullptr;
            if (ENCODE) { w0 = We[k]; w1 = We[64 + k]; w2 = We[128 + k]; bk = be[k]; }
            else        { xp = Xb + k; }

            auto zf = [&](int j) -> float {
                if ((unsigned)j < (unsigned)NNODES) {
                    float x;
                    if (ENCODE) {
                        const float* lp = Xb + j * 3;
                        x = bk + lp[0] * w0 + lp[1] * w1 + lp[2] * w2;
                    } else {
                        x = xp[(size_t)j * D_IN];
                    }
                    return dinvs[j - n0 + 9] * x;
                }
                return 0.f;
            };

            float wsum = 0.f;
            #pragma unroll
            for (int dj = -9; dj <= 9; ++dj) wsum += zf(n0 + r0 + dj);
            #pragma unroll
            for (int rr = 0; rr < 16; ++rr) {
                int r = r0 + rr;
                if (rr > 0) wsum += zf(n0 + r + 9) - zf(n0 + r - 10);
                Ys[r * YS_STR + kk] = dinvs[r + 9] * wsum;
            }
        }
        __syncthreads();

        // ---- GEMM: acc[8x8] += Ys[rows] * Ws ----
        const float4* Ys4 = (const float4*)Ys;
        const float4* Ws4 = (const float4*)Ws;
        #pragma unroll
        for (int g = 0; g < KT / 4; ++g) {
            float4 xv[8];
            #pragma unroll
            for (int i = 0; i < 8; ++i)
                xv[i] = Ys4[(ry + 16 * i) * (YS_STR / 4) + g];
            #pragma unroll
            for (int q = 0; q < 4; ++q) {
                float4 wa = Ws4[(g * 4 + q) * (WS_STR / 4) + cx * 2];
                float4 wb = Ws4[(g * 4 + q) * (WS_STR / 4) + cx * 2 + 1];
                #pragma unroll
                for (int i = 0; i < 8; ++i) {
                    float x = (q == 0) ? xv[i].x : (q == 1) ? xv[i].y
                            : (q == 2) ? xv[i].z : xv[i].w;
                    acc[i][0] += x * wa.x; acc[i][1] += x * wa.y;
                    acc[i][2] += x * wa.z; acc[i][3] += x * wa.w;
                    acc[i][4] += x * wb.x; acc[i][5] += x * wb.y;
                    acc[i][6] += x * wb.z; acc[i][7] += x * wb.w;
                }
            }
        }
    }

    const float4 bv0 = *(const float4*)(bias + c0 + cx * 8);
    const float4 bv1 = *(const float4*)(bias + c0 + cx * 8 + 4);

    if (!POOL) {
        #pragma unroll
        for (int i = 0; i < 8; ++i) {
            int node = n0 + ry + 16 * i;
            if (node < NNODES) {
                float4 o0, o1;
                o0.x = fmaxf(acc[i][0] + bv0.x, 0.f);
                o0.y = fmaxf(acc[i][1] + bv0.y, 0.f);
                o0.z = fmaxf(acc[i][2] + bv0.z, 0.f);
                o0.w = fmaxf(acc[i][3] + bv0.w, 0.f);
                o1.x = fmaxf(acc[i][4] + bv1.x, 0.f);
                o1.y = fmaxf(acc[i][5] + bv1.y, 0.f);
                o1.z = fmaxf(acc[i][6] + bv1.z, 0.f);
                o1.w = fmaxf(acc[i][7] + bv1.w, 0.f);
                float* op = Out + ((size_t)b * NNODES + node) * dot + c0 + cx * 8;
                *(float4*)op       = o0;
                *(float4*)(op + 4) = o1;
            }
        }
    } else {
        // column partial sums of relu(acc+b) over this block's valid nodes
        float ps[8];
        #pragma unroll
        for (int j = 0; j < 8; ++j) ps[j] = 0.f;
        #pragma unroll
        for (int i = 0; i < 8; ++i) {
            int node = n0 + ry + 16 * i;
            if (node < NNODES) {
                ps[0] += fmaxf(acc[i][0] + bv0.x, 0.f);
                ps[1] += fmaxf(acc[i][1] + bv0.y, 0.f);
                ps[2] += fmaxf(acc[i][2] + bv0.z, 0.f);
                ps[3] += fmaxf(acc[i][3] + bv0.w, 0.f);
                ps[4] += fmaxf(acc[i][4] + bv1.x, 0.f);
                ps[5] += fmaxf(acc[i][5] + bv1.y, 0.f);
                ps[6] += fmaxf(acc[i][6] + bv1.z, 0.f);
                ps[7] += fmaxf(acc[i][7] + bv1.w, 0.f);
            }
        }
        __syncthreads();             // all GEMM reads of Ys done
        float* red = Ys;             // [16][128]
        #pragma unroll
        for (int j = 0; j < 8; ++j) red[ry * 128 + cx * 8 + j] = ps[j];
        __syncthreads();
        if (tid < 128) {
            float s = 0.f;
            #pragma unroll
            for (int r2 = 0; r2 < 16; ++r2) s += red[r2 * 128 + tid];
            Out[((size_t)b * 4 + tile) * 128 + tid] = s;   // partial[b][tile][c]
        }
    }
}

// ---------------------------------------------------------------------------
// gf[b,c] = (sum_t partial[b][t][c]) / 468
// ---------------------------------------------------------------------------
__global__ __launch_bounds__(256) void reduce_pool(
    const float* __restrict__ partial, float* __restrict__ gf)
{
    int i = blockIdx.x * 256 + threadIdx.x;
    if (i < 128 * 128) {
        int b = i >> 7, c = i & 127;
        const float* p = partial + (size_t)b * 512;
        gf[i] = (p[c] + p[128 + c] + p[256 + c] + p[384 + c]) * (1.0f / 468.0f);
    }
}

// ---------------------------------------------------------------------------
// Head: features = relu(gf @ Wf + bf); out = features @ Wc + bc
// ---------------------------------------------------------------------------
__global__ __launch_bounds__(512) void head_kernel(
    const float* __restrict__ gf_all, const float* __restrict__ Wf,
    const float* __restrict__ bf, const float* __restrict__ Wc,
    const float* __restrict__ bc, float* __restrict__ dout)
{
    __shared__ float gfs[128];
    __shared__ float feats[512];
    int b = blockIdx.x, t = threadIdx.x;
    if (t < 128) gfs[t] = gf_all[b * 128 + t];
    __syncthreads();
    float a = bf[t];
    for (int k = 0; k < 128; ++k) a += gfs[k] * Wf[k * 512 + t];
    a = fmaxf(a, 0.f);
    dout[256 + b * 512 + t] = a;   // features region
    feats[t] = a;
    __syncthreads();
    if (t < 64) {
        float s0 = 0.f, s1 = 0.f;
        for (int c = t; c < 512; c += 64) {
            float f = feats[c];
            s0 += f * Wc[c * 2 + 0];
            s1 += f * Wc[c * 2 + 1];
        }
        #pragma unroll
        for (int off = 32; off; off >>= 1) {
            s0 += __shfl_down(s0, off);
            s1 += __shfl_down(s1, off);
        }
        if (t == 0) {
            dout[b * 2 + 0] = s0 + bc[0];
            dout[b * 2 + 1] = s1 + bc[1];
        }
    }
}

// ---------------------------------------------------------------------------
extern "C" void kernel_launch(void* const* d_in, const int* in_sizes, int n_in,
                              void* d_out, int out_size, void* d_ws, size_t ws_size,
                              hipStream_t stream)
{
    const float* landmarks = (const float*)d_in[0];
    const float* W_enc     = (const float*)d_in[1];
    const float* b_enc     = (const float*)d_in[2];
    const float* W1        = (const float*)d_in[3];
    const float* b1        = (const float*)d_in[4];
    const float* W2        = (const float*)d_in[5];
    const float* b2        = (const float*)d_in[6];
    const float* W3        = (const float*)d_in[7];
    const float* b3        = (const float*)d_in[8];
    const float* W_fus     = (const float*)d_in[9];
    const float* b_fus     = (const float*)d_in[10];
    const float* W_cls     = (const float*)d_in[11];
    const float* b_cls     = (const float*)d_in[12];
    float* out = (float*)d_out;

    char* ws = (char*)d_ws;
    float* X1      = (float*)ws;                                  // 30,670,848 B
    float* X2      = (float*)(ws + (size_t)30670848);             // 61,341,696 B
    float* partial = (float*)(ws + (size_t)30670848 + 61341696);  //    262,144 B

    // d_out layout: [0,256) logits | [256,65792) features | [65792,82176) graph_features
    float* gf = out + 65792;

    // layer1: encoder fused, D_IN=64, d_out=128
    gcn<64, true, false, 2><<<dim3(4, 128, 1), 256, 0, stream>>>(
        landmarks, W1, b1, X1, W_enc, b_enc, 128);
    // layer2: D_IN=128, d_out=256
    gcn<128, false, false, 3><<<dim3(4, 128, 2), 256, 0, stream>>>(
        X1, W2, b2, X2, nullptr, nullptr, 256);
    // layer3: D_IN=256, d_out=128, pool fused (emits per-tile partial sums)
    gcn<256, false, true, 2><<<dim3(4, 128, 1), 256, 0, stream>>>(
        X2, W3, b3, partial, nullptr, nullptr, 128);

    reduce_pool<<<64, 256, 0, stream>>>(partial, gf);
    head_kernel<<<128, 512, 0, stream>>>(gf, W_fus, b_fus, W_cls, b_cls, out);
}

// Round 3
// 506.005 us; speedup vs baseline: 1.4858x; 1.4858x over previous
//
#include <hip/hip_runtime.h>

#define NNODES 468
#define NT 128        // output nodes per block
#define KT 32         // k-tile
#define DOB 128       // output columns per block
#define XS_STR 32     // Xs row stride (floats) — bank = kk, conflict-free
#define YS_STR 36     // Ys row stride (floats)
#define WS_STR 132    // Ws row stride (floats)

// ---------------------------------------------------------------------------
// Fused GCN layer, aggregate-first:  Out = relu( ((A@X) @ W) + bias )
//   A banded (|i-j|<=9 + self), norm separable: Y[i]=dinv[i]*sum dinv[j]X[j]
// LDS: S1 holds Xs[146][32] during rolling, then Ws[32][132] during GEMM.
// ENCODE: X computed on the fly from landmarks. POOL: emit column partials.
// ---------------------------------------------------------------------------
template<int D_IN, bool ENCODE, bool POOL>
__global__ __launch_bounds__(256, 4) void gcn(
    const float* __restrict__ Xin, const float* __restrict__ W,
    const float* __restrict__ bias, float* __restrict__ Out,
    const float* __restrict__ We, const float* __restrict__ be,
    int dot)
{
    __shared__ __align__(16) float S1[146 * XS_STR];   // 4672 f (>= Ws 4224 f)
    __shared__ __align__(16) float Ys[NT * YS_STR];    // 4608 f
    __shared__ float dinvs[148];

    const int tid  = threadIdx.x;
    const int tile = blockIdx.x;
    const int b    = blockIdx.y;
    const int c0   = blockIdx.z * DOB;
    const int n0   = tile * NT;

    if (tid < 148) {
        int node = n0 - 9 + tid;
        int lo = node - 9; if (lo < 0) lo = 0;
        int hi = node + 9; if (hi > NNODES - 1) hi = NNODES - 1;
        int deg = hi - lo + 1; if (deg < 1) deg = 1;
        dinvs[tid] = 1.0f / sqrtf((float)deg);
    }

    const int cx = tid & 15;    // GEMM: 16 col groups (cols cx*4 and 64+cx*4)
    const int ry = tid >> 4;    // GEMM: 16 row groups; rows ry + 16*i
    const int kk = tid & 31;    // rolling: k column within tile
    const int r0 = (tid >> 5) * 16;   // rolling: 16-row slice

    float acc[8][8];
    #pragma unroll
    for (int i = 0; i < 8; ++i)
        #pragma unroll
        for (int j = 0; j < 8; ++j) acc[i][j] = 0.f;

    const float* Xb = ENCODE ? (Xin + (size_t)b * (NNODES * 3))
                             : (Xin + (size_t)b * NNODES * D_IN);

    for (int k0 = 0; k0 < D_IN; k0 += KT) {
        // ---- 1. issue ALL global loads for this k-tile into registers ----
        float4 xr[5];
        #pragma unroll
        for (int u = 0; u < 5; ++u) {
            int idx  = tid + u * 256;           // f4 index into Xs (1168 total)
            int r    = idx >> 3;
            int c4   = (idx & 7) << 2;
            int node = n0 - 9 + r;
            float4 v = make_float4(0.f, 0.f, 0.f, 0.f);
            if ((u < 4 || tid < 144) && node >= 0 && node < NNODES) {
                if (ENCODE) {
                    const float* lp = Xb + node * 3;
                    float l0 = lp[0], l1 = lp[1], l2 = lp[2];
                    int k = k0 + c4;
                    float4 w0 = *(const float4*)(We + k);
                    float4 w1 = *(const float4*)(We + 64 + k);
                    float4 w2 = *(const float4*)(We + 128 + k);
                    float4 bb = *(const float4*)(be + k);
                    v.x = bb.x + l0 * w0.x + l1 * w1.x + l2 * w2.x;
                    v.y = bb.y + l0 * w0.y + l1 * w1.y + l2 * w2.y;
                    v.z = bb.z + l0 * w0.z + l1 * w1.z + l2 * w2.z;
                    v.w = bb.w + l0 * w0.w + l1 * w1.w + l2 * w2.w;
                } else {
                    v = *(const float4*)(Xb + (size_t)node * D_IN + k0 + c4);
                }
            }
            xr[u] = v;
        }
        float4 wr[4];
        #pragma unroll
        for (int u = 0; u < 4; ++u) {
            int idx = tid + u * 256;            // f4 index into Ws (1024 total)
            int row = idx >> 5;
            int c4  = (idx & 31) << 2;
            wr[u] = *(const float4*)(W + (size_t)(k0 + row) * dot + c0 + c4);
        }

        __syncthreads();   // prev iter's GEMM reads of S1(Ws)+Ys complete

        // ---- 2. write Xs ----
        #pragma unroll
        for (int u = 0; u < 5; ++u) {
            int idx = tid + u * 256;
            if (u < 4 || tid < 144) {
                int r  = idx >> 3;
                int c4 = (idx & 7) << 2;
                *(float4*)(S1 + r * XS_STR + c4) = xr[u];
            }
        }
        __syncthreads();   // Xs visible

        // ---- 3. rolling 19-tap band sum (reads Xs, writes Ys) ----
        {
            float wsum = 0.f;
            #pragma unroll
            for (int rr = 0; rr < 19; ++rr)
                wsum += dinvs[r0 + rr] * S1[(r0 + rr) * XS_STR + kk];
            Ys[r0 * YS_STR + kk] = dinvs[r0 + 9] * wsum;
            #pragma unroll
            for (int rr = 1; rr < 16; ++rr) {
                wsum += dinvs[r0 + 18 + rr] * S1[(r0 + 18 + rr) * XS_STR + kk]
                      - dinvs[r0 + rr - 1]  * S1[(r0 + rr - 1)  * XS_STR + kk];
                Ys[(r0 + rr) * YS_STR + kk] = dinvs[r0 + rr + 9] * wsum;
            }
        }
        __syncthreads();   // rolling reads of S1 done

        // ---- 4. write Ws into S1 ----
        #pragma unroll
        for (int u = 0; u < 4; ++u) {
            int idx = tid + u * 256;
            int row = idx >> 5;
            int c4  = (idx & 31) << 2;
            *(float4*)(S1 + row * WS_STR + c4) = wr[u];
        }
        __syncthreads();   // Ws + Ys visible

        // ---- 5. GEMM: acc[8][8] += Ys * Ws ----
        const float4* Ys4 = (const float4*)Ys;
        const float4* Ws4 = (const float4*)S1;
        #pragma unroll
        for (int g = 0; g < KT / 4; ++g) {
            float4 xv[8];
            #pragma unroll
            for (int i = 0; i < 8; ++i)
                xv[i] = Ys4[(ry + 16 * i) * (YS_STR / 4) + g];
            #pragma unroll
            for (int q = 0; q < 4; ++q) {
                float4 wa = Ws4[(g * 4 + q) * (WS_STR / 4) + cx];
                float4 wb = Ws4[(g * 4 + q) * (WS_STR / 4) + 16 + cx];
                #pragma unroll
                for (int i = 0; i < 8; ++i) {
                    float x = (q == 0) ? xv[i].x : (q == 1) ? xv[i].y
                            : (q == 2) ? xv[i].z : xv[i].w;
                    acc[i][0] += x * wa.x; acc[i][1] += x * wa.y;
                    acc[i][2] += x * wa.z; acc[i][3] += x * wa.w;
                    acc[i][4] += x * wb.x; acc[i][5] += x * wb.y;
                    acc[i][6] += x * wb.z; acc[i][7] += x * wb.w;
                }
            }
        }
    }

    const float4 bv0 = *(const float4*)(bias + c0 + cx * 4);
    const float4 bv1 = *(const float4*)(bias + c0 + 64 + cx * 4);

    if (!POOL) {
        #pragma unroll
        for (int i = 0; i < 8; ++i) {
            int node = n0 + ry + 16 * i;
            if (node < NNODES) {
                float4 o0, o1;
                o0.x = fmaxf(acc[i][0] + bv0.x, 0.f);
                o0.y = fmaxf(acc[i][1] + bv0.y, 0.f);
                o0.z = fmaxf(acc[i][2] + bv0.z, 0.f);
                o0.w = fmaxf(acc[i][3] + bv0.w, 0.f);
                o1.x = fmaxf(acc[i][4] + bv1.x, 0.f);
                o1.y = fmaxf(acc[i][5] + bv1.y, 0.f);
                o1.z = fmaxf(acc[i][6] + bv1.z, 0.f);
                o1.w = fmaxf(acc[i][7] + bv1.w, 0.f);
                float* op = Out + ((size_t)b * NNODES + node) * dot + c0;
                *(float4*)(op + cx * 4)      = o0;
                *(float4*)(op + 64 + cx * 4) = o1;
            }
        }
    } else {
        float ps[8];
        #pragma unroll
        for (int j = 0; j < 8; ++j) ps[j] = 0.f;
        #pragma unroll
        for (int i = 0; i < 8; ++i) {
            int node = n0 + ry + 16 * i;
            if (node < NNODES) {
                ps[0] += fmaxf(acc[i][0] + bv0.x, 0.f);
                ps[1] += fmaxf(acc[i][1] + bv0.y, 0.f);
                ps[2] += fmaxf(acc[i][2] + bv0.z, 0.f);
                ps[3] += fmaxf(acc[i][3] + bv0.w, 0.f);
                ps[4] += fmaxf(acc[i][4] + bv1.x, 0.f);
                ps[5] += fmaxf(acc[i][5] + bv1.y, 0.f);
                ps[6] += fmaxf(acc[i][6] + bv1.z, 0.f);
                ps[7] += fmaxf(acc[i][7] + bv1.w, 0.f);
            }
        }
        __syncthreads();            // GEMM reads of Ys complete
        float* red = Ys;            // [16][128]
        #pragma unroll
        for (int j = 0; j < 4; ++j) {
            red[ry * 128 + cx * 4 + j]      = ps[j];
            red[ry * 128 + 64 + cx * 4 + j] = ps[4 + j];
        }
        __syncthreads();
        if (tid < 128) {
            float s = 0.f;
            #pragma unroll
            for (int r2 = 0; r2 < 16; ++r2) s += red[r2 * 128 + tid];
            Out[((size_t)b * 4 + tile) * 128 + tid] = s;   // partial[b][tile][c]
        }
    }
}

// ---------------------------------------------------------------------------
// gf[b,c] = (sum_t partial[b][t][c]) / 468
// ---------------------------------------------------------------------------
__global__ __launch_bounds__(256) void reduce_pool(
    const float* __restrict__ partial, float* __restrict__ gf)
{
    int i = blockIdx.x * 256 + threadIdx.x;
    if (i < 128 * 128) {
        int b = i >> 7, c = i & 127;
        const float* p = partial + (size_t)b * 512;
        gf[i] = (p[c] + p[128 + c] + p[256 + c] + p[384 + c]) * (1.0f / 468.0f);
    }
}

// ---------------------------------------------------------------------------
// Head: features = relu(gf @ Wf + bf); out = features @ Wc + bc
// ---------------------------------------------------------------------------
__global__ __launch_bounds__(512) void head_kernel(
    const float* __restrict__ gf_all, const float* __restrict__ Wf,
    const float* __restrict__ bf, const float* __restrict__ Wc,
    const float* __restrict__ bc, float* __restrict__ dout)
{
    __shared__ float gfs[128];
    __shared__ float feats[512];
    int b = blockIdx.x, t = threadIdx.x;
    if (t < 128) gfs[t] = gf_all[b * 128 + t];
    __syncthreads();
    float a = bf[t];
    for (int k = 0; k < 128; ++k) a += gfs[k] * Wf[k * 512 + t];
    a = fmaxf(a, 0.f);
    dout[256 + b * 512 + t] = a;   // features region
    feats[t] = a;
    __syncthreads();
    if (t < 64) {
        float s0 = 0.f, s1 = 0.f;
        for (int c = t; c < 512; c += 64) {
            float f = feats[c];
            s0 += f * Wc[c * 2 + 0];
            s1 += f * Wc[c * 2 + 1];
        }
        #pragma unroll
        for (int off = 32; off; off >>= 1) {
            s0 += __shfl_down(s0, off);
            s1 += __shfl_down(s1, off);
        }
        if (t == 0) {
            dout[b * 2 + 0] = s0 + bc[0];
            dout[b * 2 + 1] = s1 + bc[1];
        }
    }
}

// ---------------------------------------------------------------------------
extern "C" void kernel_launch(void* const* d_in, const int* in_sizes, int n_in,
                              void* d_out, int out_size, void* d_ws, size_t ws_size,
                              hipStream_t stream)
{
    const float* landmarks = (const float*)d_in[0];
    const float* W_enc     = (const float*)d_in[1];
    const float* b_enc     = (const float*)d_in[2];
    const float* W1        = (const float*)d_in[3];
    const float* b1        = (const float*)d_in[4];
    const float* W2        = (const float*)d_in[5];
    const float* b2        = (const float*)d_in[6];
    const float* W3        = (const float*)d_in[7];
    const float* b3        = (const float*)d_in[8];
    const float* W_fus     = (const float*)d_in[9];
    const float* b_fus     = (const float*)d_in[10];
    const float* W_cls     = (const float*)d_in[11];
    const float* b_cls     = (const float*)d_in[12];
    float* out = (float*)d_out;

    char* ws = (char*)d_ws;
    float* X1      = (float*)ws;                                  // 30,670,848 B
    float* X2      = (float*)(ws + (size_t)30670848);             // 61,341,696 B
    float* partial = (float*)(ws + (size_t)30670848 + 61341696);  //    262,144 B

    // d_out layout: [0,256) logits | [256,65792) features | [65792,82176) graph_features
    float* gf = out + 65792;

    gcn<64, true, false><<<dim3(4, 128, 1), 256, 0, stream>>>(
        landmarks, W1, b1, X1, W_enc, b_enc, 128);
    gcn<128, false, false><<<dim3(4, 128, 2), 256, 0, stream>>>(
        X1, W2, b2, X2, nullptr, nullptr, 256);
    gcn<256, false, true><<<dim3(4, 128, 1), 256, 0, stream>>>(
        X2, W3, b3, partial, nullptr, nullptr, 128);

    reduce_pool<<<64, 256, 0, stream>>>(partial, gf);
    head_kernel<<<128, 512, 0, stream>>>(gf, W_fus, b_fus, W_cls, b_cls, out);
}

// Round 4
// 244.203 us; speedup vs baseline: 3.0787x; 2.0721x over previous
//
#include <hip/hip_runtime.h>
#include <hip/hip_bf16.h>

typedef __bf16 bf16x8 __attribute__((ext_vector_type(8)));
typedef float  f32x4  __attribute__((ext_vector_type(4)));

#define NN 468

// ---------------------------------------------------------------------------
__device__ __forceinline__ void split_bf16(float w, unsigned short* hp,
                                           unsigned short* lp) {
    __hip_bfloat16 hb = __float2bfloat16(w);
    float hf = __bfloat162float(hb);
    __hip_bfloat16 lb = __float2bfloat16(w - hf);
    *hp = *(unsigned short*)&hb;
    *lp = *(unsigned short*)&lb;
}

// ---------------------------------------------------------------------------
// band: Y = A @ X (banded normalized adjacency, |i-j|<=9 incl self-loop),
// emitted as bf16 hi/lo pair. ENCODE fuses the 3->D node encoder.
// Block: 256 threads = (256/D) slices x D columns; each thread owns NR rows
// of one column; all taps held in registers (fully static indexing).
// ---------------------------------------------------------------------------
template<int D, int NR, bool ENCODE>
__global__ __launch_bounds__(256) void band(
    const float* __restrict__ Xin, const float* __restrict__ We,
    const float* __restrict__ be, unsigned short* __restrict__ Yhi,
    unsigned short* __restrict__ Ylo)
{
    constexpr int S = 256 / D;
    const int tid = threadIdx.x;
    const int c = tid % D;
    const int s = tid / D;
    const int b = blockIdx.y;
    const int r0 = blockIdx.x * (S * NR) + s * NR;
    if (r0 >= NN) return;

    const float DV19 = 1.0f / sqrtf(19.0f);

    const float* Xb;
    float w0 = 0.f, w1 = 0.f, w2 = 0.f, bk = 0.f;
    if constexpr (ENCODE) {
        Xb = Xin + (size_t)b * (NN * 3);
        w0 = We[c]; w1 = We[64 + c]; w2 = We[128 + c]; bk = be[c];
    } else {
        Xb = Xin + (size_t)b * NN * D + c;
    }

    float z[NR + 18];
    #pragma unroll
    for (int j = 0; j < NR + 18; ++j) {
        int gj = r0 - 9 + j;
        float v = 0.f;
        if (gj >= 0 && gj < NN) {
            float x;
            if constexpr (ENCODE) {
                x = bk + Xb[gj*3]*w0 + Xb[gj*3+1]*w1 + Xb[gj*3+2]*w2;
            } else {
                x = Xb[(size_t)gj * D];
            }
            float dv = DV19;
            if (gj < 9 || gj > NN - 10) {
                int dlo = gj - 9; if (dlo < 0) dlo = 0;
                int dhi = gj + 9; if (dhi > NN - 1) dhi = NN - 1;
                dv = 1.0f / sqrtf((float)(dhi - dlo + 1));
            }
            v = x * dv;
        }
        z[j] = v;
    }
    float wsum = 0.f;
    #pragma unroll
    for (int j = 0; j < 19; ++j) wsum += z[j];
    #pragma unroll
    for (int rr = 0; rr < NR; ++rr) {
        int gj = r0 + rr;
        if (rr) wsum += z[rr + 18] - z[rr - 1];
        if (gj < NN) {
            float dv = DV19;
            if (gj < 9 || gj > NN - 10) {
                int dlo = gj - 9; if (dlo < 0) dlo = 0;
                int dhi = gj + 9; if (dhi > NN - 1) dhi = NN - 1;
                dv = 1.0f / sqrtf((float)(dhi - dlo + 1));
            }
            float y = wsum * dv;
            size_t o = ((size_t)b * NN + gj) * D + c;
            split_bf16(y, Yhi + o, Ylo + o);
        }
    }
}

// ---------------------------------------------------------------------------
// gemm: Out = relu(Y @ W + bias), Y = Yhi+Ylo bf16 split pair [Mflat][K],
// W pre-transposed bf16 [N][K] hi/lo. No LDS, no barriers in main loop:
// each wave owns a 32x64 output tile; A/B fragments loaded global->reg.
// 3 mfma per (tile, 32-k): hi*hi + hi*lo + lo*hi.
// POOL: emit per-(b,mtile) column sums of relu output instead of storing.
// ---------------------------------------------------------------------------
template<int K, bool POOL>
__global__ __launch_bounds__(256) void gemm(
    const unsigned short* __restrict__ Yh, const unsigned short* __restrict__ Yl,
    const unsigned short* __restrict__ Wh, const unsigned short* __restrict__ Wl,
    const float* __restrict__ bias, float* __restrict__ Out, int Ntot)
{
    const int tid  = threadIdx.x;
    const int lane = tid & 63;
    const int wave = tid >> 6;
    const int wm = wave >> 1, wn = wave & 1;
    const int l15 = lane & 15, lg = lane >> 4;
    const int mt8 = blockIdx.x;           // 8 tiles of 64 rows per batch
    const int b   = blockIdx.y;
    const int n0  = blockIdx.z * 128 + wn * 64;
    const int rb0 = mt8 * 64 + wm * 32;   // row-in-batch base (may exceed NN)

    f32x4 acc[2][4] = {};
    const size_t rowbase = (size_t)b * NN + rb0;

    for (int k = 0; k < K; k += 32) {
        bf16x8 a[2][2], w[4][2];
        #pragma unroll
        for (int mt = 0; mt < 2; ++mt) {
            size_t ra = (rowbase + mt * 16 + l15) * K + k + lg * 8;
            a[mt][0] = *reinterpret_cast<const bf16x8*>(Yh + ra);
            a[mt][1] = *reinterpret_cast<const bf16x8*>(Yl + ra);
        }
        #pragma unroll
        for (int nt = 0; nt < 4; ++nt) {
            size_t rb = (size_t)(n0 + nt * 16 + l15) * K + k + lg * 8;
            w[nt][0] = *reinterpret_cast<const bf16x8*>(Wh + rb);
            w[nt][1] = *reinterpret_cast<const bf16x8*>(Wl + rb);
        }
        #pragma unroll
        for (int mt = 0; mt < 2; ++mt)
        #pragma unroll
        for (int nt = 0; nt < 4; ++nt) {
            acc[mt][nt] = __builtin_amdgcn_mfma_f32_16x16x32_bf16(
                a[mt][0], w[nt][0], acc[mt][nt], 0, 0, 0);
            acc[mt][nt] = __builtin_amdgcn_mfma_f32_16x16x32_bf16(
                a[mt][0], w[nt][1], acc[mt][nt], 0, 0, 0);
            acc[mt][nt] = __builtin_amdgcn_mfma_f32_16x16x32_bf16(
                a[mt][1], w[nt][0], acc[mt][nt], 0, 0, 0);
        }
    }

    float bv[4];
    #pragma unroll
    for (int nt = 0; nt < 4; ++nt) bv[nt] = bias[n0 + nt * 16 + l15];

    if constexpr (!POOL) {
        // D layout (guide-verified): col = lane&15, row = (lane>>4)*4 + reg
        #pragma unroll
        for (int mt = 0; mt < 2; ++mt)
        #pragma unroll
        for (int nt = 0; nt < 4; ++nt)
        #pragma unroll
        for (int r = 0; r < 4; ++r) {
            int rib = rb0 + mt * 16 + lg * 4 + r;
            if (rib < NN)
                Out[((size_t)b * NN + rib) * Ntot + n0 + nt * 16 + l15] =
                    fmaxf(acc[mt][nt][r] + bv[nt], 0.f);
        }
    } else {
        __shared__ float pool[128];
        if (tid < 128) pool[tid] = 0.f;
        __syncthreads();
        #pragma unroll
        for (int nt = 0; nt < 4; ++nt) {
            float cs = 0.f;
            #pragma unroll
            for (int mt = 0; mt < 2; ++mt)
            #pragma unroll
            for (int r = 0; r < 4; ++r) {
                int rib = rb0 + mt * 16 + lg * 4 + r;
                if (rib < NN) cs += fmaxf(acc[mt][nt][r] + bv[nt], 0.f);
            }
            cs += __shfl_xor(cs, 16);
            cs += __shfl_xor(cs, 32);
            if (lane < 16) atomicAdd(&pool[wn * 64 + nt * 16 + lane], cs);
        }
        __syncthreads();
        if (tid < 128) Out[((size_t)b * 8 + mt8) * 128 + tid] = pool[tid];
    }
}

// ---------------------------------------------------------------------------
// wconv: W1/W2/W3 fp32 [K][N] -> bf16 hi/lo transposed [N][K] (fragment-ready)
// ---------------------------------------------------------------------------
__global__ __launch_bounds__(256) void wconv(
    const float* __restrict__ W1, const float* __restrict__ W2,
    const float* __restrict__ W3, unsigned short* __restrict__ wext)
{
    int i = blockIdx.x * 256 + threadIdx.x;
    float w; int off_h, off_l, idx;
    if (i < 8192) {                       // W1: K=64,  N=128
        int k = i >> 7, n = i & 127;
        w = W1[i]; idx = n * 64 + k; off_h = 0; off_l = 8192;
    } else if (i < 40960) {               // W2: K=128, N=256
        int j = i - 8192;
        int k = j >> 8, n = j & 255;
        w = W2[j]; idx = n * 128 + k; off_h = 16384; off_l = 49152;
    } else if (i < 73728) {               // W3: K=256, N=128
        int j = i - 40960;
        int k = j >> 7, n = j & 127;
        w = W3[j]; idx = n * 256 + k; off_h = 81920; off_l = 114688;
    } else return;
    split_bf16(w, wext + off_h + idx, wext + off_l + idx);
}

// ---------------------------------------------------------------------------
__global__ __launch_bounds__(256) void reduce_pool(
    const float* __restrict__ partial, float* __restrict__ gf)
{
    int i = blockIdx.x * 256 + threadIdx.x;
    if (i < 16384) {
        int b = i >> 7, c = i & 127;
        const float* p = partial + (size_t)b * 1024;
        float s = 0.f;
        #pragma unroll
        for (int t = 0; t < 8; ++t) s += p[t * 128 + c];
        gf[i] = s * (1.0f / 468.0f);
    }
}

// ---------------------------------------------------------------------------
__global__ __launch_bounds__(512) void head_kernel(
    const float* __restrict__ gf_all, const float* __restrict__ Wf,
    const float* __restrict__ bf, const float* __restrict__ Wc,
    const float* __restrict__ bc, float* __restrict__ dout)
{
    __shared__ float gfs[128];
    __shared__ float feats[512];
    int b = blockIdx.x, t = threadIdx.x;
    if (t < 128) gfs[t] = gf_all[b * 128 + t];
    __syncthreads();
    float a = bf[t];
    for (int k = 0; k < 128; ++k) a += gfs[k] * Wf[k * 512 + t];
    a = fmaxf(a, 0.f);
    dout[256 + b * 512 + t] = a;
    feats[t] = a;
    __syncthreads();
    if (t < 64) {
        float s0 = 0.f, s1 = 0.f;
        for (int c = t; c < 512; c += 64) {
            float f = feats[c];
            s0 += f * Wc[c * 2 + 0];
            s1 += f * Wc[c * 2 + 1];
        }
        #pragma unroll
        for (int off = 32; off; off >>= 1) {
            s0 += __shfl_down(s0, off);
            s1 += __shfl_down(s1, off);
        }
        if (t == 0) {
            dout[b * 2 + 0] = s0 + bc[0];
            dout[b * 2 + 1] = s1 + bc[1];
        }
    }
}

// ---------------------------------------------------------------------------
extern "C" void kernel_launch(void* const* d_in, const int* in_sizes, int n_in,
                              void* d_out, int out_size, void* d_ws, size_t ws_size,
                              hipStream_t stream)
{
    const float* landmarks = (const float*)d_in[0];
    const float* W_enc     = (const float*)d_in[1];
    const float* b_enc     = (const float*)d_in[2];
    const float* W1        = (const float*)d_in[3];
    const float* b1        = (const float*)d_in[4];
    const float* W2        = (const float*)d_in[5];
    const float* b2        = (const float*)d_in[6];
    const float* W3        = (const float*)d_in[7];
    const float* b3        = (const float*)d_in[8];
    const float* W_fus     = (const float*)d_in[9];
    const float* b_fus     = (const float*)d_in[10];
    const float* W_cls     = (const float*)d_in[11];
    const float* b_cls     = (const float*)d_in[12];
    float* out = (float*)d_out;

    // Overlapped workspace layout (peak ~118 MiB). Lifetimes:
    //  band1{Y1} gemm1{Y1,X1} band2{X1,Y2} gemm2{Y2,X2} band3{X2,Y3} gemm3{Y3}
    char* ws = (char*)d_ws;
    unsigned short* Y1h = (unsigned short*)(ws + 0);          // [0, 7.7M)
    unsigned short* Y1l = (unsigned short*)(ws + 7667712);    // [7.7M, 15.3M)
    float*          X2  = (float*)(ws + 0);                   // [0, 61.3M)
    float*          X1  = (float*)(ws + 61341696);            // [61.3M, 92.0M)
    unsigned short* Y3h = (unsigned short*)(ws + 61341696);   // over X1 (dead)
    unsigned short* Y2h = (unsigned short*)(ws + 92012544);   // [92.0M, 107.3M)
    unsigned short* Y2l = (unsigned short*)(ws + 107347968);  // [107.3M, 122.7M)
    unsigned short* Y3l = (unsigned short*)(ws + 92012544);   // over Y2 (dead)
    unsigned short* wext = (unsigned short*)(ws + 122683392); // 294,912 B
    float* partial = (float*)(ws + 122978304);                // 524,288 B

    float* gf = out + 65792;   // [0,256) logits | [256,65792) feats | gf

    wconv<<<288, 256, 0, stream>>>(W1, W2, W3, wext);

    band<64, 32, true><<<dim3(4, 128), 256, 0, stream>>>(
        landmarks, W_enc, b_enc, Y1h, Y1l);
    gemm<64, false><<<dim3(8, 128, 1), 256, 0, stream>>>(
        Y1h, Y1l, wext + 0, wext + 8192, b1, X1, 128);

    band<128, 32, false><<<dim3(8, 128), 256, 0, stream>>>(
        X1, nullptr, nullptr, Y2h, Y2l);
    gemm<128, false><<<dim3(8, 128, 2), 256, 0, stream>>>(
        Y2h, Y2l, wext + 16384, wext + 49152, b2, X2, 256);

    band<256, 32, false><<<dim3(15, 128), 256, 0, stream>>>(
        X2, nullptr, nullptr, Y3h, Y3l);
    gemm<256, true><<<dim3(8, 128, 1), 256, 0, stream>>>(
        Y3h, Y3l, wext + 81920, wext + 114688, b3, partial, 128);

    reduce_pool<<<64, 256, 0, stream>>>(partial, gf);
    head_kernel<<<128, 512, 0, stream>>>(gf, W_fus, b_fus, W_cls, b_cls, out);
}

// Round 5
// 172.631 us; speedup vs baseline: 4.3551x; 1.4146x over previous
//
#include <hip/hip_runtime.h>
#include <hip/hip_bf16.h>

typedef __bf16 bf16x8 __attribute__((ext_vector_type(8)));
typedef float  f32x4  __attribute__((ext_vector_type(4)));
typedef unsigned short ushort_t;

#define NN 468

// ---------------------------------------------------------------------------
__device__ __forceinline__ void split_bf16(float w, ushort_t* hp, ushort_t* lp) {
    __hip_bfloat16 hb = __float2bfloat16(w);
    float hf = __bfloat162float(hb);
    __hip_bfloat16 lb = __float2bfloat16(w - hf);
    *hp = *(ushort_t*)&hb;
    *lp = *(ushort_t*)&lb;
}

__device__ __forceinline__ float dinv_of(int ri) {
    // 1/sqrt(deg) for valid node, 0 for out-of-range (masks halo garbage)
    if (ri < 0 || ri >= NN) return 0.f;
    int lo = ri - 9; if (lo < 0) lo = 0;
    int hi = ri + 9; if (hi > NN - 1) hi = NN - 1;
    return 1.0f / sqrtf((float)(hi - lo + 1));
}

// ---------------------------------------------------------------------------
// band: Y = A @ X rolled per column (fp32), emitted bf16 hi/lo. ENCODE fuses
// the 3->64 node encoder. Only used for layer 1 (X = encoder(landmarks)).
// ---------------------------------------------------------------------------
template<int D, int NR, bool ENCODE>
__global__ __launch_bounds__(256) void band(
    const float* __restrict__ Xin, const float* __restrict__ We,
    const float* __restrict__ be, ushort_t* __restrict__ Yhi,
    ushort_t* __restrict__ Ylo)
{
    constexpr int S = 256 / D;
    const int tid = threadIdx.x;
    const int c = tid % D;
    const int s = tid / D;
    const int b = blockIdx.y;
    const int r0 = blockIdx.x * (S * NR) + s * NR;
    if (r0 >= NN) return;

    const float* Xb;
    float w0 = 0.f, w1 = 0.f, w2 = 0.f, bk = 0.f;
    if constexpr (ENCODE) {
        Xb = Xin + (size_t)b * (NN * 3);
        w0 = We[c]; w1 = We[64 + c]; w2 = We[128 + c]; bk = be[c];
    } else {
        Xb = Xin + (size_t)b * NN * D + c;
    }

    float z[NR + 18];
    #pragma unroll
    for (int j = 0; j < NR + 18; ++j) {
        int gj = r0 - 9 + j;
        float v = 0.f;
        if (gj >= 0 && gj < NN) {
            float x;
            if constexpr (ENCODE) {
                x = bk + Xb[gj*3]*w0 + Xb[gj*3+1]*w1 + Xb[gj*3+2]*w2;
            } else {
                x = Xb[(size_t)gj * D];
            }
            v = x * dinv_of(gj);
        }
        z[j] = v;
    }
    float wsum = 0.f;
    #pragma unroll
    for (int j = 0; j < 19; ++j) wsum += z[j];
    #pragma unroll
    for (int rr = 0; rr < NR; ++rr) {
        int gj = r0 + rr;
        if (rr) wsum += z[rr + 18] - z[rr - 1];
        if (gj < NN) {
            float y = wsum * dinv_of(gj);
            size_t o = ((size_t)b * NN + gj) * D + c;
            split_bf16(y, Yhi + o, Ylo + o);
        }
    }
}

// ---------------------------------------------------------------------------
// gemm: computes relu(Y @ W + b) on MFMA (bf16 hi/lo split, 3 mfma per k32).
// BAND: block computes 96 rows (64 out + 2x16 halo), bands them in LDS, and
//       emits NEXT layer's Y (bf16 hi/lo) directly — X never touches HBM.
// POOL: block computes 64 rows and emits per-(b,tile) column sums.
// Waves: 2m x 2n; wave tile = (MT*16) x 64.
// ---------------------------------------------------------------------------
template<int K, bool BAND, bool POOL>
__global__ __launch_bounds__(256, 4) void gemm(
    const ushort_t* __restrict__ Yh, const ushort_t* __restrict__ Yl,
    const ushort_t* __restrict__ Wh, const ushort_t* __restrict__ Wl,
    const float* __restrict__ bias, float* __restrict__ OutP,
    ushort_t* __restrict__ OYh, ushort_t* __restrict__ OYl, int Kn)
{
    constexpr int MT = BAND ? 3 : 2;            // m-tiles per wave
    constexpr int WR = MT * 16;                 // rows per wave
    __shared__ float smem[BAND ? (96 * 132 + 96) : 128];

    const int tid  = threadIdx.x;
    const int lane = tid & 63;
    const int wave = tid >> 6;
    const int wm = wave & 1, wn = wave >> 1;
    const int l15 = lane & 15, lg = lane >> 4;
    const int mt8 = blockIdx.x;                 // 8 row tiles of 64
    const int b   = blockIdx.y;
    const int c0  = blockIdx.z * 128;
    const int rb0 = mt8 * 64;
    const size_t rowbase = (size_t)b * NN;

    f32x4 acc[MT][4] = {};

    #pragma unroll
    for (int k = 0; k < K; k += 32) {
        bf16x8 a[MT][2];
        #pragma unroll
        for (int mt = 0; mt < MT; ++mt) {
            int lr = wm * WR + mt * 16 + l15;
            int ri = rb0 - (BAND ? 16 : 0) + lr;
            ri = ri < 0 ? 0 : (ri > NN - 1 ? NN - 1 : ri);   // finite garbage ok
            size_t ra = (rowbase + ri) * K + k + lg * 8;
            a[mt][0] = *reinterpret_cast<const bf16x8*>(Yh + ra);
            a[mt][1] = *reinterpret_cast<const bf16x8*>(Yl + ra);
        }
        #pragma unroll
        for (int nt = 0; nt < 4; ++nt) {
            size_t rb = (size_t)(c0 + wn * 64 + nt * 16 + l15) * K + k + lg * 8;
            bf16x8 w0 = *reinterpret_cast<const bf16x8*>(Wh + rb);
            bf16x8 w1 = *reinterpret_cast<const bf16x8*>(Wl + rb);
            #pragma unroll
            for (int mt = 0; mt < MT; ++mt) {
                acc[mt][nt] = __builtin_amdgcn_mfma_f32_16x16x32_bf16(
                    a[mt][0], w0, acc[mt][nt], 0, 0, 0);
                acc[mt][nt] = __builtin_amdgcn_mfma_f32_16x16x32_bf16(
                    a[mt][0], w1, acc[mt][nt], 0, 0, 0);
                acc[mt][nt] = __builtin_amdgcn_mfma_f32_16x16x32_bf16(
                    a[mt][1], w0, acc[mt][nt], 0, 0, 0);
            }
        }
    }

    if constexpr (BAND) {
        float* Xs    = smem;             // [96][132] fp32
        float* dinvs = smem + 96 * 132;  // [96]
        // C/D layout (verified R3): col = l15, row = lg*4 + r
        #pragma unroll
        for (int mt = 0; mt < MT; ++mt)
        #pragma unroll
        for (int nt = 0; nt < 4; ++nt)
        #pragma unroll
        for (int r = 0; r < 4; ++r) {
            int lr = wm * WR + mt * 16 + lg * 4 + r;
            int cl = wn * 64 + nt * 16 + l15;
            Xs[lr * 132 + cl] = fmaxf(acc[mt][nt][r] + bias[c0 + cl], 0.f);
        }
        if (tid < 96) dinvs[tid] = dinv_of(rb0 - 16 + tid);
        __syncthreads();

        // rolling 19-tap band per column; thread owns (col, 32-row half)
        const int c    = tid & 127;
        const int oo0  = (tid >> 7) * 32;
        float wsum = 0.f;
        #pragma unroll
        for (int d = 0; d < 19; ++d)
            wsum += dinvs[oo0 + 7 + d] * Xs[(oo0 + 7 + d) * 132 + c];
        #pragma unroll
        for (int rr = 0; rr < 32; ++rr) {
            int oo = oo0 + rr;
            if (rr) wsum += dinvs[oo + 25] * Xs[(oo + 25) * 132 + c]
                          - dinvs[oo + 6]  * Xs[(oo + 6)  * 132 + c];
            int ro = rb0 + oo;
            if (ro < NN) {
                float y = wsum * dinvs[oo + 16];
                size_t o = (rowbase + ro) * Kn + c0 + c;
                split_bf16(y, OYh + o, OYl + o);
            }
        }
    } else {   // POOL
        float* pool = smem;   // [128]
        if (tid < 128) pool[tid] = 0.f;
        __syncthreads();
        float bv[4];
        #pragma unroll
        for (int nt = 0; nt < 4; ++nt) bv[nt] = bias[c0 + wn * 64 + nt * 16 + l15];
        #pragma unroll
        for (int nt = 0; nt < 4; ++nt) {
            float cs = 0.f;
            #pragma unroll
            for (int mt = 0; mt < MT; ++mt)
            #pragma unroll
            for (int r = 0; r < 4; ++r) {
                int rib = rb0 + wm * WR + mt * 16 + lg * 4 + r;
                if (rib < NN) cs += fmaxf(acc[mt][nt][r] + bv[nt], 0.f);
            }
            cs += __shfl_xor(cs, 16);
            cs += __shfl_xor(cs, 32);
            if (lane < 16) atomicAdd(&pool[wn * 64 + nt * 16 + lane], cs);
        }
        __syncthreads();
        if (tid < 128) OutP[((size_t)b * 8 + mt8) * 128 + tid] = pool[tid];
    }
}

// ---------------------------------------------------------------------------
// wconv: W1/W2/W3 fp32 [K][N] -> bf16 hi/lo transposed [N][K]
// ---------------------------------------------------------------------------
__global__ __launch_bounds__(256) void wconv(
    const float* __restrict__ W1, const float* __restrict__ W2,
    const float* __restrict__ W3, ushort_t* __restrict__ wext)
{
    int i = blockIdx.x * 256 + threadIdx.x;
    float w; int off_h, off_l, idx;
    if (i < 8192) {                       // W1: K=64,  N=128
        int k = i >> 7, n = i & 127;
        w = W1[i]; idx = n * 64 + k; off_h = 0; off_l = 8192;
    } else if (i < 40960) {               // W2: K=128, N=256
        int j = i - 8192;
        int k = j >> 8, n = j & 255;
        w = W2[j]; idx = n * 128 + k; off_h = 16384; off_l = 49152;
    } else if (i < 73728) {               // W3: K=256, N=128
        int j = i - 40960;
        int k = j >> 7, n = j & 127;
        w = W3[j]; idx = n * 256 + k; off_h = 81920; off_l = 114688;
    } else return;
    split_bf16(w, wext + off_h + idx, wext + off_l + idx);
}

// ---------------------------------------------------------------------------
__global__ __launch_bounds__(256) void reduce_pool(
    const float* __restrict__ partial, float* __restrict__ gf)
{
    int i = blockIdx.x * 256 + threadIdx.x;
    if (i < 16384) {
        int b = i >> 7, c = i & 127;
        const float* p = partial + (size_t)b * 1024;
        float s = 0.f;
        #pragma unroll
        for (int t = 0; t < 8; ++t) s += p[t * 128 + c];
        gf[i] = s * (1.0f / 468.0f);
    }
}

// ---------------------------------------------------------------------------
__global__ __launch_bounds__(512) void head_kernel(
    const float* __restrict__ gf_all, const float* __restrict__ Wf,
    const float* __restrict__ bf, const float* __restrict__ Wc,
    const float* __restrict__ bc, float* __restrict__ dout)
{
    __shared__ float gfs[128];
    __shared__ float feats[512];
    int b = blockIdx.x, t = threadIdx.x;
    if (t < 128) gfs[t] = gf_all[b * 128 + t];
    __syncthreads();
    float a = bf[t];
    for (int k = 0; k < 128; ++k) a += gfs[k] * Wf[k * 512 + t];
    a = fmaxf(a, 0.f);
    dout[256 + b * 512 + t] = a;
    feats[t] = a;
    __syncthreads();
    if (t < 64) {
        float s0 = 0.f, s1 = 0.f;
        for (int c = t; c < 512; c += 64) {
            float f = feats[c];
            s0 += f * Wc[c * 2 + 0];
            s1 += f * Wc[c * 2 + 1];
        }
        #pragma unroll
        for (int off = 32; off; off >>= 1) {
            s0 += __shfl_down(s0, off);
            s1 += __shfl_down(s1, off);
        }
        if (t == 0) {
            dout[b * 2 + 0] = s0 + bc[0];
            dout[b * 2 + 1] = s1 + bc[1];
        }
    }
}

// ---------------------------------------------------------------------------
extern "C" void kernel_launch(void* const* d_in, const int* in_sizes, int n_in,
                              void* d_out, int out_size, void* d_ws, size_t ws_size,
                              hipStream_t stream)
{
    const float* landmarks = (const float*)d_in[0];
    const float* W_enc     = (const float*)d_in[1];
    const float* b_enc     = (const float*)d_in[2];
    const float* W1        = (const float*)d_in[3];
    const float* b1        = (const float*)d_in[4];
    const float* W2        = (const float*)d_in[5];
    const float* b2        = (const float*)d_in[6];
    const float* W3        = (const float*)d_in[7];
    const float* b3        = (const float*)d_in[8];
    const float* W_fus     = (const float*)d_in[9];
    const float* b_fus     = (const float*)d_in[10];
    const float* W_cls     = (const float*)d_in[11];
    const float* b_cls     = (const float*)d_in[12];
    float* out = (float*)d_out;

    // Workspace (no overlap needed, ~108 MB):
    char* ws = (char*)d_ws;
    ushort_t* Y1h = (ushort_t*)(ws + 0);            // 59904*64*2  = 7,667,712
    ushort_t* Y1l = (ushort_t*)(ws + 7667712);
    ushort_t* Y2h = (ushort_t*)(ws + 15335424);     // 59904*128*2 = 15,335,424
    ushort_t* Y2l = (ushort_t*)(ws + 30670848);
    ushort_t* Y3h = (ushort_t*)(ws + 46006272);     // 59904*256*2 = 30,670,848
    ushort_t* Y3l = (ushort_t*)(ws + 76677120);
    ushort_t* wext = (ushort_t*)(ws + 107347968);   // 294,912
    float* partial = (float*)(ws + 107642880);      // 524,288

    float* gf = out + 65792;   // [0,256) logits | [256,65792) feats | gf

    wconv<<<288, 256, 0, stream>>>(W1, W2, W3, wext);

    // layer1: band(encoder) -> Y1; gemm1 emits Y2 directly (band fused)
    band<64, 32, true><<<dim3(4, 128), 256, 0, stream>>>(
        landmarks, W_enc, b_enc, Y1h, Y1l);
    gemm<64, true, false><<<dim3(8, 128, 1), 256, 0, stream>>>(
        Y1h, Y1l, wext + 0, wext + 8192, b1, nullptr, Y2h, Y2l, 128);

    // layer2: gemm2 emits Y3 directly
    gemm<128, true, false><<<dim3(8, 128, 2), 256, 0, stream>>>(
        Y2h, Y2l, wext + 16384, wext + 49152, b2, nullptr, Y3h, Y3l, 256);

    // layer3: gemm3 pools
    gemm<256, false, true><<<dim3(8, 128, 1), 256, 0, stream>>>(
        Y3h, Y3l, wext + 81920, wext + 114688, b3, partial, nullptr, nullptr, 0);

    reduce_pool<<<64, 256, 0, stream>>>(partial, gf);
    head_kernel<<<128, 512, 0, stream>>>(gf, W_fus, b_fus, W_cls, b_cls, out);
}

// Round 6
// 129.843 us; speedup vs baseline: 5.7902x; 1.3295x over previous
//
#include <hip/hip_runtime.h>
#include <hip/hip_bf16.h>

typedef __bf16 bf16x8 __attribute__((ext_vector_type(8)));
typedef float  f32x4  __attribute__((ext_vector_type(4)));
typedef unsigned short ushort_t;

#define NN 468
#define RPAD 480          // rows per batch, padded to 16
#define NTILES 30         // RPAD/16

// ---------------------------------------------------------------------------
__device__ __forceinline__ void split_bf16(float w, ushort_t* hp, ushort_t* lp) {
    __hip_bfloat16 hb = __float2bfloat16(w);
    float hf = __bfloat162float(hb);
    __hip_bfloat16 lb = __float2bfloat16(w - hf);
    *hp = *(ushort_t*)&hb;
    *lp = *(ushort_t*)&lb;
}

__device__ __forceinline__ float dinv_of(int ri) {
    if (ri < 0 || ri >= NN) return 0.f;       // masks halo/pad rows
    int lo = ri - 9; if (lo < 0) lo = 0;
    int hi = ri + 9; if (hi > NN - 1) hi = NN - 1;
    return 1.0f / sqrtf((float)(hi - lo + 1));
}

// Fragment-major layout: lane l of a 16x32 MFMA tile holds row=(l&15),
// k=(l>>4)*8+j at offset l*8+j. Verified mapping (R3/R4 passed).
__device__ __forceinline__ size_t frag_addr(int r, int k, int K) {
    return (size_t)(r >> 4) * (16 * K) + ((k >> 5)) * 512
         + ((k >> 3) & 3) * 128 + (r & 15) * 8 + (k & 7);
}

// ---------------------------------------------------------------------------
// band1: Y1 = A @ encoder(landmarks), emitted bf16 hi/lo in fragment layout.
// Pad rows [468,480) written as zeros.
// ---------------------------------------------------------------------------
__global__ __launch_bounds__(256) void band1(
    const float* __restrict__ Lm, const float* __restrict__ We,
    const float* __restrict__ be, ushort_t* __restrict__ Yhi,
    ushort_t* __restrict__ Ylo)
{
    const int tid = threadIdx.x;
    const int c = tid & 63;
    const int s = tid >> 6;
    const int b = blockIdx.y;
    const int r0 = blockIdx.x * 128 + s * 32;
    if (r0 >= RPAD) return;

    const float* Xb = Lm + (size_t)b * (NN * 3);
    const float w0 = We[c], w1 = We[64 + c], w2 = We[128 + c], bk = be[c];

    float z[50];
    #pragma unroll
    for (int j = 0; j < 50; ++j) {
        int gj = r0 - 9 + j;
        float v = 0.f;
        if (gj >= 0 && gj < NN) {
            float x = bk + Xb[gj*3]*w0 + Xb[gj*3+1]*w1 + Xb[gj*3+2]*w2;
            v = x * dinv_of(gj);
        }
        z[j] = v;
    }
    float wsum = 0.f;
    #pragma unroll
    for (int j = 0; j < 19; ++j) wsum += z[j];
    ushort_t* Yh = Yhi + (size_t)b * RPAD * 64;
    ushort_t* Yl = Ylo + (size_t)b * RPAD * 64;
    #pragma unroll
    for (int rr = 0; rr < 32; ++rr) {
        int gj = r0 + rr;
        if (rr) wsum += z[rr + 18] - z[rr - 1];
        if (gj < RPAD) {
            float y = (gj < NN) ? wsum * dinv_of(gj) : 0.f;
            size_t o = frag_addr(gj, c, 64);
            split_bf16(y, Yh + o, Yl + o);
        }
    }
}

// ---------------------------------------------------------------------------
// gemm: relu(Y @ W + b) via MFMA bf16 hi/lo split (3 mfma / k32).
// All Y and W operands in fragment-major layout -> every load is one
// contiguous 1KB transaction (base + lane*8).
// BAND: 96 staged rows (64 out + 16+16 halo), band in LDS, emits next Y.
// POOL: 64 rows, emits per-(b,tile) column sums.
// ---------------------------------------------------------------------------
template<int K, bool BAND, bool POOL>
__global__ __launch_bounds__(256, 3) void gemm(
    const ushort_t* __restrict__ Yh, const ushort_t* __restrict__ Yl,
    const ushort_t* __restrict__ Wh, const ushort_t* __restrict__ Wl,
    const float* __restrict__ bias, float* __restrict__ OutP,
    ushort_t* __restrict__ OYh, ushort_t* __restrict__ OYl, int Kn)
{
    constexpr int MT = BAND ? 3 : 2;            // m-tiles per wave
    __shared__ float smem[BAND ? (96 * 132 + 96) : 128];

    const int tid  = threadIdx.x;
    const int lane = tid & 63;
    const int wave = tid >> 6;
    const int wm = wave & 1, wn = wave >> 1;
    const int l15 = lane & 15, lg = lane >> 4;
    const int mt8 = blockIdx.x;                 // 8 row tiles of 64
    const int b   = blockIdx.y;
    const int c0  = blockIdx.z * 128;
    const int rb0 = mt8 * 64;

    const ushort_t* Yhb = Yh + (size_t)b * RPAD * K;
    const ushort_t* Ylb = Yl + (size_t)b * RPAD * K;

    f32x4 acc[MT][4] = {};

    #pragma unroll
    for (int k0 = 0; k0 < K; k0 += 32) {
        const int ko = (k0 >> 5) * 512;
        bf16x8 a[MT][2];
        #pragma unroll
        for (int mt = 0; mt < MT; ++mt) {
            int t = mt8 * 4 + (BAND ? -1 : 0) + wm * MT + mt;
            t = t < 0 ? 0 : (t > NTILES - 1 ? NTILES - 1 : t);
            const ushort_t* ph = Yhb + (size_t)t * (16 * K) + ko + lane * 8;
            a[mt][0] = *reinterpret_cast<const bf16x8*>(ph);
            a[mt][1] = *reinterpret_cast<const bf16x8*>(
                           Ylb + (size_t)t * (16 * K) + ko + lane * 8);
        }
        #pragma unroll
        for (int nt = 0; nt < 4; ++nt) {
            int ntile = (c0 >> 4) + wn * 4 + nt;
            size_t woff = (size_t)ntile * (16 * K) + ko + lane * 8;
            bf16x8 w0 = *reinterpret_cast<const bf16x8*>(Wh + woff);
            bf16x8 w1 = *reinterpret_cast<const bf16x8*>(Wl + woff);
            #pragma unroll
            for (int mt = 0; mt < MT; ++mt) {
                acc[mt][nt] = __builtin_amdgcn_mfma_f32_16x16x32_bf16(
                    a[mt][0], w0, acc[mt][nt], 0, 0, 0);
                acc[mt][nt] = __builtin_amdgcn_mfma_f32_16x16x32_bf16(
                    a[mt][0], w1, acc[mt][nt], 0, 0, 0);
                acc[mt][nt] = __builtin_amdgcn_mfma_f32_16x16x32_bf16(
                    a[mt][1], w0, acc[mt][nt], 0, 0, 0);
            }
        }
    }

    if constexpr (BAND) {
        float* Xs    = smem;             // [96][132] fp32
        float* dinvs = smem + 96 * 132;  // [96]
        // C/D layout (verified): col = l15, row = lg*4 + r
        #pragma unroll
        for (int mt = 0; mt < MT; ++mt)
        #pragma unroll
        for (int nt = 0; nt < 4; ++nt)
        #pragma unroll
        for (int r = 0; r < 4; ++r) {
            int lr = wm * 48 + mt * 16 + lg * 4 + r;
            int cl = wn * 64 + nt * 16 + l15;
            Xs[lr * 132 + cl] = fmaxf(acc[mt][nt][r] + bias[c0 + cl], 0.f);
        }
        if (tid < 96) dinvs[tid] = dinv_of(rb0 - 16 + tid);
        __syncthreads();

        const int c   = tid & 127;
        const int oo0 = (tid >> 7) * 32;
        const int cc  = c0 + c;
        ushort_t* Oh = OYh + (size_t)b * RPAD * Kn;
        ushort_t* Ol = OYl + (size_t)b * RPAD * Kn;
        float wsum = 0.f;
        #pragma unroll
        for (int d = 0; d < 19; ++d)
            wsum += dinvs[oo0 + 7 + d] * Xs[(oo0 + 7 + d) * 132 + c];
        #pragma unroll
        for (int rr = 0; rr < 32; ++rr) {
            int oo = oo0 + rr;
            if (rr) wsum += dinvs[oo + 25] * Xs[(oo + 25) * 132 + c]
                          - dinvs[oo + 6]  * Xs[(oo + 6)  * 132 + c];
            int gr = rb0 + oo;
            if (gr < RPAD) {
                float y = (gr < NN) ? wsum * dinvs[oo + 16] : 0.f;
                size_t o = frag_addr(gr, cc, Kn);
                split_bf16(y, Oh + o, Ol + o);
            }
        }
    } else {   // POOL
        float* pool = smem;
        if (tid < 128) pool[tid] = 0.f;
        __syncthreads();
        float bv[4];
        #pragma unroll
        for (int nt = 0; nt < 4; ++nt) bv[nt] = bias[c0 + wn * 64 + nt * 16 + l15];
        #pragma unroll
        for (int nt = 0; nt < 4; ++nt) {
            float cs = 0.f;
            #pragma unroll
            for (int mt = 0; mt < MT; ++mt)
            #pragma unroll
            for (int r = 0; r < 4; ++r) {
                int rib = rb0 + wm * 32 + mt * 16 + lg * 4 + r;
                if (rib < NN) cs += fmaxf(acc[mt][nt][r] + bv[nt], 0.f);
            }
            cs += __shfl_xor(cs, 16);
            cs += __shfl_xor(cs, 32);
            if (lane < 16) atomicAdd(&pool[wn * 64 + nt * 16 + lane], cs);
        }
        __syncthreads();
        if (tid < 128) OutP[((size_t)b * 8 + mt8) * 128 + tid] = pool[tid];
    }
}

// ---------------------------------------------------------------------------
// wconv: W fp32 [K][N] -> bf16 hi/lo planes in B-fragment layout [ntile][...]
// ---------------------------------------------------------------------------
__global__ __launch_bounds__(256) void wconv(
    const float* __restrict__ W1, const float* __restrict__ W2,
    const float* __restrict__ W3, ushort_t* __restrict__ wext)
{
    int i = blockIdx.x * 256 + threadIdx.x;
    float w; int off_h, off_l; size_t idx;
    if (i < 8192) {                       // W1: K=64,  N=128
        int k = i >> 7, n = i & 127;
        w = W1[i]; idx = frag_addr(n, k, 64);  off_h = 0;     off_l = 8192;
    } else if (i < 40960) {               // W2: K=128, N=256
        int j = i - 8192;
        int k = j >> 8, n = j & 255;
        w = W2[j]; idx = frag_addr(n, k, 128); off_h = 16384; off_l = 49152;
    } else if (i < 73728) {               // W3: K=256, N=128
        int j = i - 40960;
        int k = j >> 7, n = j & 127;
        w = W3[j]; idx = frag_addr(n, k, 256); off_h = 81920; off_l = 114688;
    } else return;
    split_bf16(w, wext + off_h + idx, wext + off_l + idx);
}

// ---------------------------------------------------------------------------
__global__ __launch_bounds__(256) void reduce_pool(
    const float* __restrict__ partial, float* __restrict__ gf)
{
    int i = blockIdx.x * 256 + threadIdx.x;
    if (i < 16384) {
        int b = i >> 7, c = i & 127;
        const float* p = partial + (size_t)b * 1024;
        float s = 0.f;
        #pragma unroll
        for (int t = 0; t < 8; ++t) s += p[t * 128 + c];
        gf[i] = s * (1.0f / 468.0f);
    }
}

// ---------------------------------------------------------------------------
__global__ __launch_bounds__(512) void head_kernel(
    const float* __restrict__ gf_all, const float* __restrict__ Wf,
    const float* __restrict__ bf, const float* __restrict__ Wc,
    const float* __restrict__ bc, float* __restrict__ dout)
{
    __shared__ float gfs[128];
    __shared__ float feats[512];
    int b = blockIdx.x, t = threadIdx.x;
    if (t < 128) gfs[t] = gf_all[b * 128 + t];
    __syncthreads();
    float a = bf[t];
    for (int k = 0; k < 128; ++k) a += gfs[k] * Wf[k * 512 + t];
    a = fmaxf(a, 0.f);
    dout[256 + b * 512 + t] = a;
    feats[t] = a;
    __syncthreads();
    if (t < 64) {
        float s0 = 0.f, s1 = 0.f;
        for (int c = t; c < 512; c += 64) {
            float f = feats[c];
            s0 += f * Wc[c * 2 + 0];
            s1 += f * Wc[c * 2 + 1];
        }
        #pragma unroll
        for (int off = 32; off; off >>= 1) {
            s0 += __shfl_down(s0, off);
            s1 += __shfl_down(s1, off);
        }
        if (t == 0) {
            dout[b * 2 + 0] = s0 + bc[0];
            dout[b * 2 + 1] = s1 + bc[1];
        }
    }
}

// ---------------------------------------------------------------------------
extern "C" void kernel_launch(void* const* d_in, const int* in_sizes, int n_in,
                              void* d_out, int out_size, void* d_ws, size_t ws_size,
                              hipStream_t stream)
{
    const float* landmarks = (const float*)d_in[0];
    const float* W_enc     = (const float*)d_in[1];
    const float* b_enc     = (const float*)d_in[2];
    const float* W1        = (const float*)d_in[3];
    const float* b1        = (const float*)d_in[4];
    const float* W2        = (const float*)d_in[5];
    const float* b2        = (const float*)d_in[6];
    const float* W3        = (const float*)d_in[7];
    const float* b3        = (const float*)d_in[8];
    const float* W_fus     = (const float*)d_in[9];
    const float* b_fus     = (const float*)d_in[10];
    const float* W_cls     = (const float*)d_in[11];
    const float* b_cls     = (const float*)d_in[12];
    float* out = (float*)d_out;

    // Workspace (fragment-major Y planes, 480 rows/batch):
    char* ws = (char*)d_ws;
    ushort_t* Y1h = (ushort_t*)(ws + 0);            // 128*480*64*2  = 7,864,320
    ushort_t* Y1l = (ushort_t*)(ws + 7864320);
    ushort_t* Y2h = (ushort_t*)(ws + 15728640);     // 128*480*128*2 = 15,728,640
    ushort_t* Y2l = (ushort_t*)(ws + 31457280);
    ushort_t* Y3h = (ushort_t*)(ws + 47185920);     // 128*480*256*2 = 31,457,280
    ushort_t* Y3l = (ushort_t*)(ws + 78643200);
    ushort_t* wext = (ushort_t*)(ws + 110100480);   // 294,912
    float* partial = (float*)(ws + 110395392);      // 524,288

    float* gf = out + 65792;   // [0,256) logits | [256,65792) feats | gf

    wconv<<<288, 256, 0, stream>>>(W1, W2, W3, wext);

    band1<<<dim3(4, 128), 256, 0, stream>>>(landmarks, W_enc, b_enc, Y1h, Y1l);

    gemm<64, true, false><<<dim3(8, 128, 1), 256, 0, stream>>>(
        Y1h, Y1l, wext + 0, wext + 8192, b1, nullptr, Y2h, Y2l, 128);

    gemm<128, true, false><<<dim3(8, 128, 2), 256, 0, stream>>>(
        Y2h, Y2l, wext + 16384, wext + 49152, b2, nullptr, Y3h, Y3l, 256);

    gemm<256, false, true><<<dim3(8, 128, 1), 256, 0, stream>>>(
        Y3h, Y3l, wext + 81920, wext + 114688, b3, partial, nullptr, nullptr, 0);

    reduce_pool<<<64, 256, 0, stream>>>(partial, gf);
    head_kernel<<<128, 512, 0, stream>>>(gf, W_fus, b_fus, W_cls, b_cls, out);
}